// Round 7
// baseline (342.344 us; speedup 1.0000x reference)
//
#include <hip/hip_runtime.h>
#include <stdint.h>

#define M_DIM 8192
#define N_DIM 4096
#define K_DIM 4224
#define BK 64

typedef float f32x16 __attribute__((ext_vector_type(16)));
typedef int   i32x8  __attribute__((ext_vector_type(8)));
typedef int   i32x4  __attribute__((ext_vector_type(4)));

#define RAW_BARRIER()  asm volatile("s_barrier" ::: "memory")
#define WAIT_VM0()     asm volatile("s_waitcnt vmcnt(0)" ::: "memory")

// ---------------------------------------------------------------------------
// fp4(e2m1) nibble + per-16 E8M0 scale -> exact bf8(e5m2), pure VALU.
// ---------------------------------------------------------------------------
__device__ __forceinline__ uint32_t conv4(uint32_t x, uint32_t k1) {
    uint32_t n7   = x & 0x07070707u;
    uint32_t base = __builtin_amdgcn_perm(0x46444240u, 0x3E3C3800u, n7);
    uint32_t nz   = __builtin_amdgcn_perm(0x01010101u, 0x01010100u, n7);
    uint32_t sign = (x & 0x08080808u) << 4;
    return (base + nz * k1 - (nz << 6)) | sign;
}

// 32 elements (2 scale-blocks) per thread; BW-bound (~30us, r5-verified).
__global__ __launch_bounds__(256) void dequant_all(
    const int* __restrict__ Ap, const int* __restrict__ SFA, uint8_t* __restrict__ Aout,
    const int* __restrict__ Bp, const int* __restrict__ SFB, uint8_t* __restrict__ Bout)
{
    const int nhA = M_DIM * K_DIM / 32;
    int i = blockIdx.x * 256 + threadIdx.x;
    const int* p; const int* sf; uint8_t* out; int idx;
    if (i < nhA) { p = Ap; sf = SFA; out = Aout; idx = i; }
    else         { p = Bp; sf = SFB; out = Bout; idx = i - nhA; }

    const int4* p4 = (const int4*)p;
    int4 q0 = p4[4 * idx];
    int4 q1 = p4[4 * idx + 1];
    int4 q2 = p4[4 * idx + 2];
    int4 q3 = p4[4 * idx + 3];
    int2 sfp = ((const int2*)sf)[idx];
    uint32_t k1a = (uint32_t)(((sfp.x - 127) << 2) + 64);
    uint32_t k1b = (uint32_t)(((sfp.y - 127) << 2) + 64);

    uint32_t o[8];
#pragma unroll
    for (int g = 0; g < 4; ++g) {
        int4 pg = (g == 0) ? q0 : (g == 1) ? q1 : (g == 2) ? q2 : q3;
        uint32_t k1 = (g < 2) ? k1a : k1b;
        uint32_t w = (uint32_t)(pg.x & 0xFF) | ((uint32_t)(pg.y & 0xFF) << 8) |
                     ((uint32_t)(pg.z & 0xFF) << 16) | ((uint32_t)pg.w << 24);
        uint32_t lr = conv4(w & 0x0F0F0F0Fu, k1);
        uint32_t hr = conv4((w >> 4) & 0x0F0F0F0Fu, k1);
        o[2 * g]     = __builtin_amdgcn_perm(hr, lr, 0x05010400u); // elems 0..3
        o[2 * g + 1] = __builtin_amdgcn_perm(hr, lr, 0x07030602u); // elems 4..7
    }
    *(uint4*)(out + (size_t)idx * 32)      = make_uint4(o[0], o[1], o[2], o[3]);
    *(uint4*)(out + (size_t)idx * 32 + 16) = make_uint4(o[4], o[5], o[6], o[7]);
}

// ---------------------------------------------------------------------------
// GEMM via MX-scaled MFMA at unity scale: C = scale*(A.B^T) + bias
// 256x256 tile, 8 waves (2Mx4N), BK=64, bf8 operands, 4 LDS buffers.
// Round-6: BARRIER PER TWO TILES (33 syncs, was 66). r3-r5 analysis:
// per-SIMD MFMA floor 1100cy (=measured 49% MfmaUtil), LDS busy ~1850cy,
// budget 2418cy -> ~570cy/tile of barrier-convoy dead time. Keep the full
// read-ahead schedule; sync (vmcnt(0)+s_barrier) only after ODD tiles.
// Safety (both parities tabulated):
//  - tile x staged at iter x-3; confirmed by sync at end of iter x-3
//    rounded up to odd => always >=1 barrier before any wave's read.
//  - stage(t+3) -> buf[(t-1)%4]: its readers ran in iter t-2, separated
//    by the end-of-(t-1 | t-2) barrier.
//  - vmcnt(0) at odd-iter end drains loads >=1 CORE (~2300cy) old => cheap.
//  - prologue vmcnt(0) confirms tiles 0,1,2 (iter 1 read-ahead of tile 2).
// ---------------------------------------------------------------------------
__global__ __launch_bounds__(512, 2) void gemm_mx(
    const uint8_t* __restrict__ A, const uint8_t* __restrict__ B,
    const float* __restrict__ scale, const float* __restrict__ bias,
    float* __restrict__ C)
{
    __shared__ uint8_t smem[131072];
    // buf k at offset k*32768: A [256][64] at +0, B [256][64] at +16384

    const int tid  = threadIdx.x;
    const int lane = tid & 63;
    const int w    = tid >> 6;      // 0..7
    const int wm   = w >> 2;        // 0..1 : 128-row band
    const int wn   = w & 3;         // 0..3 : 64-col band
    const int r31  = lane & 31;
    const int h    = lane >> 5;

    // XCD-aware swizzle: 512 blocks total, chunk of 64 consecutive per XCD
    const int lin = blockIdx.y * 16 + blockIdx.x;        // gridDim.x == 16
    const int o   = (lin & 7) * 64 + (lin >> 3);         // bijective (512 % 8 == 0)
    const int bn0 = (o & 15) * 256;
    const int bm0 = (o >> 4) * 256;

    f32x16 acc[4][2];
#pragma unroll
    for (int i = 0; i < 4; ++i)
#pragma unroll
        for (int j = 0; j < 2; ++j)
            acc[i][j] = (f32x16)(0.0f);

    // staging: wave w stages rows [w*32, w*32+32) of A and of B,
    // 2 issues of 16 rows x 64B per matrix (4 global_load_lds per wave per tile).
    const int srow = lane >> 2;
    const int scol = (((lane & 3) ^ ((lane >> 3) & 3)) << 4);
    const uint8_t* Ag = A + (size_t)(bm0 + w * 32 + srow) * K_DIM + scol;
    const uint8_t* Bg = B + (size_t)(bn0 + w * 32 + srow) * K_DIM + scol;
    uint8_t* Asw = smem + w * 2048;
    uint8_t* Bsw = smem + 16384 + w * 2048;

#define STAGE(koff, boff)                                                        \
    do {                                                                         \
        const uint8_t* ag_ = Ag + (koff);                                        \
        const uint8_t* bg_ = Bg + (koff);                                        \
        __builtin_amdgcn_global_load_lds(                                        \
            (const __attribute__((address_space(1))) void*)(ag_),                \
            (__attribute__((address_space(3))) void*)(Asw + (boff)), 16, 0, 0);  \
        __builtin_amdgcn_global_load_lds(                                        \
            (const __attribute__((address_space(1))) void*)(ag_ + (size_t)16 * K_DIM), \
            (__attribute__((address_space(3))) void*)(Asw + (boff) + 1024), 16, 0, 0); \
        __builtin_amdgcn_global_load_lds(                                        \
            (const __attribute__((address_space(1))) void*)(bg_),                \
            (__attribute__((address_space(3))) void*)(Bsw + (boff)), 16, 0, 0);  \
        __builtin_amdgcn_global_load_lds(                                        \
            (const __attribute__((address_space(1))) void*)(bg_ + (size_t)16 * K_DIM), \
            (__attribute__((address_space(3))) void*)(Bsw + (boff) + 1024), 16, 0, 0); \
    } while (0)

    // swizzled, kt-invariant fragment addresses (buf0; bufk = +k*32768)
    const int sx = (r31 >> 1) & 3;
    const uint8_t* pa_lo[4]; const uint8_t* pa_hi[4];
    const uint8_t* pb_lo[2]; const uint8_t* pb_hi[2];
#pragma unroll
    for (int mi = 0; mi < 4; ++mi) {
        const uint8_t* base = smem + (wm * 128 + mi * 32 + r31) * 64;
        pa_lo[mi] = base + (((2 * h)     ^ sx) << 4);
        pa_hi[mi] = base + (((2 * h + 1) ^ sx) << 4);
    }
#pragma unroll
    for (int ni = 0; ni < 2; ++ni) {
        const uint8_t* base = smem + 16384 + (wn * 64 + ni * 32 + r31) * 64;
        pb_lo[ni] = base + (((2 * h)     ^ sx) << 4);
        pb_hi[ni] = base + (((2 * h + 1) ^ sx) << 4);
    }

    i32x8 afX0[2], afX1[2], bfX0[2], bfX1[2], afY[2];

    auto rd = [&](const uint8_t* plo, const uint8_t* phi, int off, i32x8& dst) {
        i32x4 lo = *(const i32x4*)(plo + off);
        i32x4 hi = *(const i32x4*)(phi + off);
        dst = __builtin_shufflevector(lo, hi, 0, 1, 2, 3, 4, 5, 6, 7);
    };
    auto mm = [&](const i32x8& a, const i32x8& b, f32x16& c) {
        c = __builtin_amdgcn_mfma_scale_f32_32x32x64_f8f6f4(
                a, b, c, 1, 1, 0, 0x7F7F7F7F, 0, 0x7F7F7F7F);
    };

// iteration t (read-ahead): cluster0 on (AC,BC) [read during t-1];
// read af01/bf01(t+1)->AN/BN; cluster1 on (afY,BC); read af23(t+1)->afY.
#define CORE(AC, BC, AN, BN, OBN)                             \
    __builtin_amdgcn_s_setprio(1);                            \
    mm(AC[0], BC[0], acc[0][0]); mm(AC[0], BC[1], acc[0][1]); \
    mm(AC[1], BC[0], acc[1][0]); mm(AC[1], BC[1], acc[1][1]); \
    __builtin_amdgcn_s_setprio(0);                            \
    rd(pa_lo[0], pa_hi[0], OBN, AN[0]);                       \
    rd(pa_lo[1], pa_hi[1], OBN, AN[1]);                       \
    rd(pb_lo[0], pb_hi[0], OBN, BN[0]);                       \
    rd(pb_lo[1], pb_hi[1], OBN, BN[1]);                       \
    __builtin_amdgcn_s_setprio(1);                            \
    mm(afY[0], BC[0], acc[2][0]); mm(afY[0], BC[1], acc[2][1]); \
    mm(afY[1], BC[0], acc[3][0]); mm(afY[1], BC[1], acc[3][1]); \
    __builtin_amdgcn_s_setprio(0);                            \
    rd(pa_lo[2], pa_hi[2], OBN, afY[0]);                      \
    rd(pa_lo[3], pa_hi[3], OBN, afY[1]);

// even tile: stage + core, NO sync
#define BODYE(T, AC, BC, AN, BN, OBN, OBS)                    \
    STAGE(((T) + 3) * BK, OBS);                               \
    CORE(AC, BC, AN, BN, OBN)

// odd tile: stage + core + pair-end sync
#define BODYO(T, AC, BC, AN, BN, OBN, OBS)                    \
    STAGE(((T) + 3) * BK, OBS);                               \
    CORE(AC, BC, AN, BN, OBN)                                 \
    WAIT_VM0(); RAW_BARRIER();

    // prologue: stage tiles 0,1,2 -> buf0,1,2; vmcnt(0) confirms all three
    // (tile 2 is read-ahead during iter 1, before the first in-loop sync).
    STAGE(0 * BK, 0);
    STAGE(1 * BK, 32768);
    STAGE(2 * BK, 65536);
    WAIT_VM0();
    RAW_BARRIER();
    // fragments of tile 0 (buf0)
    rd(pa_lo[0], pa_hi[0], 0, afX0[0]);
    rd(pa_lo[1], pa_hi[1], 0, afX0[1]);
    rd(pb_lo[0], pb_hi[0], 0, bfX0[0]);
    rd(pb_lo[1], pb_hi[1], 0, bfX0[1]);
    rd(pa_lo[2], pa_hi[2], 0, afY[0]);
    rd(pa_lo[3], pa_hi[3], 0, afY[1]);

    // main: t = 0..59, unroll 4 (buf of t+1 = (t+1)%4, stage buf = (t+3)%4)
#pragma unroll 1
    for (int g = 0; g < 15; ++g) {
        const int t = 4 * g;
        BODYE(t,     afX0, bfX0, afX1, bfX1, 32768, 98304)
        BODYO(t + 1, afX1, bfX1, afX0, bfX0, 65536, 0)
        BODYE(t + 2, afX0, bfX0, afX1, bfX1, 98304, 32768)
        BODYO(t + 3, afX1, bfX1, afX0, bfX0, 0,     65536)
    }
    // tail: t = 60,61,62 still stage (63,64,65)
    BODYE(60, afX0, bfX0, afX1, bfX1, 32768, 98304)   // stage 63
    BODYO(61, afX1, bfX1, afX0, bfX0, 65536, 0)       // stage 64, sync
    BODYE(62, afX0, bfX0, afX1, bfX1, 98304, 32768)   // stage 65
    // t=63: no stage; reads frags(64) [staged iter 61, confirmed end-61];
    // vmcnt(0) drains stage 65 (1 iter old), barrier.
    CORE(afX1, bfX1, afX0, bfX0, 0)
    WAIT_VM0(); RAW_BARRIER();
    // t=64: reads frags(65) [staged iter 62, confirmed end-63]; no more DMA.
    CORE(afX0, bfX0, afX1, bfX1, 32768)
    // t=65: clusters only
    __builtin_amdgcn_s_setprio(1);
    mm(afX1[0], bfX1[0], acc[0][0]); mm(afX1[0], bfX1[1], acc[0][1]);
    mm(afX1[1], bfX1[0], acc[1][0]); mm(afX1[1], bfX1[1], acc[1][1]);
    mm(afY[0],  bfX1[0], acc[2][0]); mm(afY[0],  bfX1[1], acc[2][1]);
    mm(afY[1],  bfX1[0], acc[3][0]); mm(afY[1],  bfX1[1], acc[3][1]);
    __builtin_amdgcn_s_setprio(0);
#undef BODYE
#undef BODYO
#undef CORE
#undef STAGE

    const float sc = scale[0];
#pragma unroll
    for (int ni = 0; ni < 2; ++ni) {
        const int col = bn0 + wn * 64 + ni * 32 + r31;
        const float bv = bias[col];
#pragma unroll
        for (int mi = 0; mi < 4; ++mi) {
            const int rbase = bm0 + wm * 128 + mi * 32 + 4 * h;
#pragma unroll
            for (int reg = 0; reg < 16; ++reg) {
                const int row = rbase + (reg & 3) + 8 * (reg >> 2);
                C[(size_t)row * N_DIM + col] = sc * acc[mi][ni][reg] + bv;
            }
        }
    }
}

extern "C" void kernel_launch(void* const* d_in, const int* in_sizes, int n_in,
                              void* d_out, int out_size, void* d_ws, size_t ws_size,
                              hipStream_t stream) {
    const int*   A_packed = (const int*)d_in[0];
    const int*   SFA      = (const int*)d_in[1];
    const float* scale    = (const float*)d_in[2];
    const int*   B_packed = (const int*)d_in[3];
    const int*   SFB      = (const int*)d_in[4];
    const float* bias     = (const float*)d_in[5];
    float*       out      = (float*)d_out;

    uint8_t* Abf8 = (uint8_t*)d_ws;
    uint8_t* Bbf8 = Abf8 + (size_t)M_DIM * K_DIM;

    const int npairA = M_DIM * K_DIM / 32;  // 1,081,344
    const int npairB = N_DIM * K_DIM / 32;  //   540,672
    dequant_all<<<(npairA + npairB) / 256, 256, 0, stream>>>(
        A_packed, SFA, Abf8, B_packed, SFB, Bbf8);   // 6336 blocks

    dim3 grid(N_DIM / 256, M_DIM / 256);    // (16, 32) = 512 blocks
    gemm_mx<<<grid, 512, 0, stream>>>(Abf8, Bbf8, scale, bias, out);
}

// Round 8
// 336.773 us; speedup vs baseline: 1.0165x; 1.0165x over previous
//
#include <hip/hip_runtime.h>
#include <stdint.h>

#define M_DIM 8192
#define N_DIM 4096
#define K_DIM 4224
#define BK 64

typedef float f32x16 __attribute__((ext_vector_type(16)));
typedef int   i32x8  __attribute__((ext_vector_type(8)));
typedef int   i32x4  __attribute__((ext_vector_type(4)));

#define RAW_BARRIER()  asm volatile("s_barrier" ::: "memory")
#define WAIT_VM8()     asm volatile("s_waitcnt vmcnt(8)" ::: "memory")
#define WAIT_VM0()     asm volatile("s_waitcnt vmcnt(0)" ::: "memory")

// ---------------------------------------------------------------------------
// fp4(e2m1) nibble + per-16 E8M0 scale -> exact bf8(e5m2), pure VALU.
// ---------------------------------------------------------------------------
__device__ __forceinline__ uint32_t conv4(uint32_t x, uint32_t k1) {
    uint32_t n7   = x & 0x07070707u;
    uint32_t base = __builtin_amdgcn_perm(0x46444240u, 0x3E3C3800u, n7);
    uint32_t nz   = __builtin_amdgcn_perm(0x01010101u, 0x01010100u, n7);
    uint32_t sign = (x & 0x08080808u) << 4;
    return (base + nz * k1 - (nz << 6)) | sign;
}

// 32 elements (2 scale-blocks) per thread; BW-bound (~30us, r5-verified).
__global__ __launch_bounds__(256) void dequant_all(
    const int* __restrict__ Ap, const int* __restrict__ SFA, uint8_t* __restrict__ Aout,
    const int* __restrict__ Bp, const int* __restrict__ SFB, uint8_t* __restrict__ Bout)
{
    const int nhA = M_DIM * K_DIM / 32;
    int i = blockIdx.x * 256 + threadIdx.x;
    const int* p; const int* sf; uint8_t* out; int idx;
    if (i < nhA) { p = Ap; sf = SFA; out = Aout; idx = i; }
    else         { p = Bp; sf = SFB; out = Bout; idx = i - nhA; }

    const int4* p4 = (const int4*)p;
    int4 q0 = p4[4 * idx];
    int4 q1 = p4[4 * idx + 1];
    int4 q2 = p4[4 * idx + 2];
    int4 q3 = p4[4 * idx + 3];
    int2 sfp = ((const int2*)sf)[idx];
    uint32_t k1a = (uint32_t)(((sfp.x - 127) << 2) + 64);
    uint32_t k1b = (uint32_t)(((sfp.y - 127) << 2) + 64);

    uint32_t o[8];
#pragma unroll
    for (int g = 0; g < 4; ++g) {
        int4 pg = (g == 0) ? q0 : (g == 1) ? q1 : (g == 2) ? q2 : q3;
        uint32_t k1 = (g < 2) ? k1a : k1b;
        uint32_t w = (uint32_t)(pg.x & 0xFF) | ((uint32_t)(pg.y & 0xFF) << 8) |
                     ((uint32_t)(pg.z & 0xFF) << 16) | ((uint32_t)pg.w << 24);
        uint32_t lr = conv4(w & 0x0F0F0F0Fu, k1);
        uint32_t hr = conv4((w >> 4) & 0x0F0F0F0Fu, k1);
        o[2 * g]     = __builtin_amdgcn_perm(hr, lr, 0x05010400u); // elems 0..3
        o[2 * g + 1] = __builtin_amdgcn_perm(hr, lr, 0x07030602u); // elems 4..7
    }
    *(uint4*)(out + (size_t)idx * 32)      = make_uint4(o[0], o[1], o[2], o[3]);
    *(uint4*)(out + (size_t)idx * 32 + 16) = make_uint4(o[4], o[5], o[6], o[7]);
}

// ---------------------------------------------------------------------------
// GEMM via MX-scaled MFMA at unity scale: C = scale*(A.B^T) + bias
// Round-7: 4 WAVES (1/SIMD), per-wave output 128x128 (acc[4][4]).
// r3-r6 analysis: LDS read traffic was the saturated resource (8 waves ->
// 96 b128 reads per 32KB tile, ~1850cy vs 1100cy MFMA floor; schedule
// changes all null). Wave grid 2Mx2N halves the sharing: 64 reads/tile
// (-33%), ~1300-1500cy, near-balanced with MFMA. Schedule identical to r3:
// 4 LDS buffers, stage-ahead-3, FULL READ-AHEAD (frags of t+1 read during
// t in each cluster's shadow), per-tile counted vmcnt(8) (8 loads/wave/tile
// now), one barrier/tile. 1 wave/SIMD is safe here: no in-loop latency
// waits (operands 1 tile old, vmcnt targets 2-iter-old loads).
// VGPR: 256 acc + 128 frags + ~35 addr ~ 420 (launch_bounds(256,1)).
// ---------------------------------------------------------------------------
__global__ __launch_bounds__(256, 1) void gemm_mx(
    const uint8_t* __restrict__ A, const uint8_t* __restrict__ B,
    const float* __restrict__ scale, const float* __restrict__ bias,
    float* __restrict__ C)
{
    __shared__ uint8_t smem[131072];
    // buf k at offset k*32768: A [256][64] at +0, B [256][64] at +16384

    const int tid  = threadIdx.x;
    const int lane = tid & 63;
    const int w    = tid >> 6;      // 0..3
    const int wm   = w >> 1;        // 0..1 : 128-row band
    const int wn   = w & 1;         // 0..1 : 128-col band
    const int r31  = lane & 31;
    const int h    = lane >> 5;

    // XCD-aware swizzle: 512 blocks total, chunk of 64 consecutive per XCD
    const int lin = blockIdx.y * 16 + blockIdx.x;        // gridDim.x == 16
    const int o   = (lin & 7) * 64 + (lin >> 3);         // bijective (512 % 8 == 0)
    const int bn0 = (o & 15) * 256;
    const int bm0 = (o >> 4) * 256;

    f32x16 acc[4][4];
#pragma unroll
    for (int i = 0; i < 4; ++i)
#pragma unroll
        for (int j = 0; j < 4; ++j)
            acc[i][j] = (f32x16)(0.0f);

    // staging: wave w stages rows [w*64, w*64+64) of A and of B,
    // 4 gl_lds of 16 rows x 64B per matrix (8 loads per wave per tile).
    // lane slot = local_row*4 + g''; fetch global granule g = g''^((row>>1)&3)
    const int srow = lane >> 2;
    const int scol = (((lane & 3) ^ ((lane >> 3) & 3)) << 4);
    const uint8_t* Ag = A + (size_t)(bm0 + w * 64 + srow) * K_DIM + scol;
    const uint8_t* Bg = B + (size_t)(bn0 + w * 64 + srow) * K_DIM + scol;
    uint8_t* Asw = smem + w * 4096;
    uint8_t* Bsw = smem + 16384 + w * 4096;

#define GLDS(gp, lp)                                                             \
    __builtin_amdgcn_global_load_lds(                                            \
        (const __attribute__((address_space(1))) void*)(gp),                     \
        (__attribute__((address_space(3))) void*)(lp), 16, 0, 0)

#define STAGE(koff, boff)                                                        \
    do {                                                                         \
        const uint8_t* ag_ = Ag + (koff);                                        \
        const uint8_t* bg_ = Bg + (koff);                                        \
        GLDS(ag_,                       Asw + (boff));                           \
        GLDS(ag_ + (size_t)16 * K_DIM,  Asw + (boff) + 1024);                    \
        GLDS(ag_ + (size_t)32 * K_DIM,  Asw + (boff) + 2048);                    \
        GLDS(ag_ + (size_t)48 * K_DIM,  Asw + (boff) + 3072);                    \
        GLDS(bg_,                       Bsw + (boff));                           \
        GLDS(bg_ + (size_t)16 * K_DIM,  Bsw + (boff) + 1024);                    \
        GLDS(bg_ + (size_t)32 * K_DIM,  Bsw + (boff) + 2048);                    \
        GLDS(bg_ + (size_t)48 * K_DIM,  Bsw + (boff) + 3072);                    \
    } while (0)

    // swizzled, kt-invariant fragment addresses (buf0; bufk = +k*32768)
    const int sx = (r31 >> 1) & 3;
    const uint8_t* pa_lo[4]; const uint8_t* pa_hi[4];
    const uint8_t* pb_lo[4]; const uint8_t* pb_hi[4];
#pragma unroll
    for (int mi = 0; mi < 4; ++mi) {
        const uint8_t* base = smem + (wm * 128 + mi * 32 + r31) * 64;
        pa_lo[mi] = base + (((2 * h)     ^ sx) << 4);
        pa_hi[mi] = base + (((2 * h + 1) ^ sx) << 4);
    }
#pragma unroll
    for (int ni = 0; ni < 4; ++ni) {
        const uint8_t* base = smem + 16384 + (wn * 128 + ni * 32 + r31) * 64;
        pb_lo[ni] = base + (((2 * h)     ^ sx) << 4);
        pb_hi[ni] = base + (((2 * h + 1) ^ sx) << 4);
    }

    i32x8 afX0[4], afX1[4], bfX0[4], bfX1[4];

    auto rd = [&](const uint8_t* plo, const uint8_t* phi, int off, i32x8& dst) {
        i32x4 lo = *(const i32x4*)(plo + off);
        i32x4 hi = *(const i32x4*)(phi + off);
        dst = __builtin_shufflevector(lo, hi, 0, 1, 2, 3, 4, 5, 6, 7);
    };
    auto mm = [&](const i32x8& a, const i32x8& b, f32x16& c) {
        c = __builtin_amdgcn_mfma_scale_f32_32x32x64_f8f6f4(
                a, b, c, 1, 1, 0, 0x7F7F7F7F, 0, 0x7F7F7F7F);
    };

// iteration t: 4 clusters by mi (4 MFMAs each) on (AC,BC) [read during t-1];
// each cluster's shadow reads one af + one bf fragment-pair of tile t+1.
#define CLUSTER(AC, BC, MI)                                   \
    __builtin_amdgcn_s_setprio(1);                            \
    mm(AC[MI], BC[0], acc[MI][0]); mm(AC[MI], BC[1], acc[MI][1]); \
    mm(AC[MI], BC[2], acc[MI][2]); mm(AC[MI], BC[3], acc[MI][3]); \
    __builtin_amdgcn_s_setprio(0);

#define CORE(AC, BC, AN, BN, OBN)                             \
    CLUSTER(AC, BC, 0)                                        \
    rd(pa_lo[0], pa_hi[0], OBN, AN[0]);                       \
    rd(pb_lo[0], pb_hi[0], OBN, BN[0]);                       \
    CLUSTER(AC, BC, 1)                                        \
    rd(pa_lo[1], pa_hi[1], OBN, AN[1]);                       \
    rd(pb_lo[1], pb_hi[1], OBN, BN[1]);                       \
    CLUSTER(AC, BC, 2)                                        \
    rd(pa_lo[2], pa_hi[2], OBN, AN[2]);                       \
    rd(pb_lo[2], pb_hi[2], OBN, BN[2]);                       \
    CLUSTER(AC, BC, 3)                                        \
    rd(pa_lo[3], pa_hi[3], OBN, AN[3]);                       \
    rd(pb_lo[3], pb_hi[3], OBN, BN[3]);

#define BODY(T, AC, BC, AN, BN, OBN, OBS)                     \
    STAGE(((T) + 3) * BK, OBS);                               \
    CORE(AC, BC, AN, BN, OBN)                                 \
    WAIT_VM8(); RAW_BARRIER();

    // prologue: stage tiles 0,1,2 -> buf0,1,2 (24 loads); vmcnt(8) confirms
    // tiles 0 AND 1 (iter 0 read-ahead of tile 1 is barrier-covered).
    STAGE(0 * BK, 0);
    STAGE(1 * BK, 32768);
    STAGE(2 * BK, 65536);
    WAIT_VM8();
    RAW_BARRIER();
    // fragments of tile 0 (buf0)
    rd(pa_lo[0], pa_hi[0], 0, afX0[0]);
    rd(pa_lo[1], pa_hi[1], 0, afX0[1]);
    rd(pa_lo[2], pa_hi[2], 0, afX0[2]);
    rd(pa_lo[3], pa_hi[3], 0, afX0[3]);
    rd(pb_lo[0], pb_hi[0], 0, bfX0[0]);
    rd(pb_lo[1], pb_hi[1], 0, bfX0[1]);
    rd(pb_lo[2], pb_hi[2], 0, bfX0[2]);
    rd(pb_lo[3], pb_hi[3], 0, bfX0[3]);

    // main: t = 0..59, unroll 4 (buf of t+1 = (t+1)%4, stage buf = (t+3)%4)
#pragma unroll 1
    for (int g = 0; g < 15; ++g) {
        BODY(4 * g,     afX0, bfX0, afX1, bfX1, 32768, 98304)
        BODY(4 * g + 1, afX1, bfX1, afX0, bfX0, 65536, 0)
        BODY(4 * g + 2, afX0, bfX0, afX1, bfX1, 98304, 32768)
        BODY(4 * g + 3, afX1, bfX1, afX0, bfX0, 0,     65536)
    }
    // tail: t = 60,61,62 still stage (63,64,65)
    BODY(60, afX0, bfX0, afX1, bfX1, 32768, 98304)   // stage 63 -> buf3
    BODY(61, afX1, bfX1, afX0, bfX0, 65536, 0)       // stage 64 -> buf0
    BODY(62, afX0, bfX0, afX1, bfX1, 98304, 32768)   // stage 65 -> buf1
    // t=63: no stage; reads frags(64) [buf0; confirmed end-62]; vmcnt(0)
    // drains tile 65's loads (1 iter old), barrier.
    CORE(afX1, bfX1, afX0, bfX0, 0)
    WAIT_VM0(); RAW_BARRIER();
    // t=64: reads frags(65) [buf1; confirmed]; no more DMA -> no barrier.
    CORE(afX0, bfX0, afX1, bfX1, 32768)
    // t=65: clusters only
    CLUSTER(afX1, bfX1, 0)
    CLUSTER(afX1, bfX1, 1)
    CLUSTER(afX1, bfX1, 2)
    CLUSTER(afX1, bfX1, 3)
#undef BODY
#undef CORE
#undef CLUSTER
#undef STAGE
#undef GLDS

    const float sc = scale[0];
#pragma unroll
    for (int ni = 0; ni < 4; ++ni) {
        const int col = bn0 + wn * 128 + ni * 32 + r31;
        const float bv = bias[col];
#pragma unroll
        for (int mi = 0; mi < 4; ++mi) {
            const int rbase = bm0 + wm * 128 + mi * 32 + 4 * h;
#pragma unroll
            for (int reg = 0; reg < 16; ++reg) {
                const int row = rbase + (reg & 3) + 8 * (reg >> 2);
                C[(size_t)row * N_DIM + col] = sc * acc[mi][ni][reg] + bv;
            }
        }
    }
}

extern "C" void kernel_launch(void* const* d_in, const int* in_sizes, int n_in,
                              void* d_out, int out_size, void* d_ws, size_t ws_size,
                              hipStream_t stream) {
    const int*   A_packed = (const int*)d_in[0];
    const int*   SFA      = (const int*)d_in[1];
    const float* scale    = (const float*)d_in[2];
    const int*   B_packed = (const int*)d_in[3];
    const int*   SFB      = (const int*)d_in[4];
    const float* bias     = (const float*)d_in[5];
    float*       out      = (float*)d_out;

    uint8_t* Abf8 = (uint8_t*)d_ws;
    uint8_t* Bbf8 = Abf8 + (size_t)M_DIM * K_DIM;

    const int npairA = M_DIM * K_DIM / 32;  // 1,081,344
    const int npairB = N_DIM * K_DIM / 32;  //   540,672
    dequant_all<<<(npairA + npairB) / 256, 256, 0, stream>>>(
        A_packed, SFA, Abf8, B_packed, SFB, Bbf8);   // 6336 blocks

    dim3 grid(N_DIM / 256, M_DIM / 256);    // (16, 32) = 512 blocks
    gemm_mx<<<grid, 256, 0, stream>>>(Abf8, Bbf8, scale, bias, out);
}